// Round 6
// baseline (140.421 us; speedup 1.0000x reference)
//
#include <hip/hip_runtime.h>
#include <hip/hip_bf16.h>

#define IN_CH 256
#define OUT_CH 128
#define NCAT 256          // concatenated output channels (sup | gat)
#define CAP 64            // bucket capacity per row (Poisson(16): P(>64) ~ 1e-13)

typedef __attribute__((ext_vector_type(8))) short bf16x8;
typedef __attribute__((ext_vector_type(4))) float f32x4;

__device__ __forceinline__ unsigned short f2bf(float f) {
  unsigned int u = __builtin_bit_cast(unsigned int, f);
  u += 0x7FFFu + ((u >> 16) & 1u);           // round-to-nearest-even
  return (unsigned short)(u >> 16);
}
__device__ __forceinline__ unsigned int pack2bf(float a, float b) {
  return (unsigned int)f2bf(a) | ((unsigned int)f2bf(b) << 16);
}
__device__ __forceinline__ float bflo(unsigned int u) {
  return __builtin_bit_cast(float, u << 16);
}
__device__ __forceinline__ float bfhi(unsigned int u) {
  return __builtin_bit_cast(float, u & 0xFFFF0000u);
}

// ---------------------------------------------------------------------------
// Init: cnt = 0 (blocks [0,cntBlocks)) and WcatT build (next 256 blocks).
// WcatT[c][k] bf16, c in [0,256): c<128 -> w[k][c], c>=128 -> gw[k][c-128].
// ---------------------------------------------------------------------------
__global__ __launch_bounds__(256) void init_and_wcat(
    const float* __restrict__ w, const float* __restrict__ gw,
    unsigned short* __restrict__ wcatT, int* __restrict__ cnt,
    int nrows, int cntBlocks) {
  const int b = blockIdx.x;
  if (b < cntBlocks) {
    const int i = b * 256 + threadIdx.x;
    if (i < nrows) cnt[i] = 0;
  } else {
    const int c = b - cntBlocks;          // 0..255
    const int k = threadIdx.x;            // 0..255
    const float v = (c < 128) ? w[(size_t)k * 128 + c]
                              : gw[(size_t)k * 128 + (c - 128)];
    wcatT[(size_t)c * 256 + k] = f2bf(v);
  }
}

// ---------------------------------------------------------------------------
// Fat kernel. Blocks [0,bktBlocks): edge scatter into per-row buckets (runs
// FIRST so it co-resides under the GEMM blocks). Blocks [bktBlocks,...):
// MFMA GEMM, tile 128 rows x all 256 cols -> block owns complete comb rows.
//
// comb layout: row r = 512 B; channel-pair p at byte 8p:
//   [sup_{2p}, sup_{2p+1}, gat_{2p}, gat_{2p+1}] bf16.
// Epilogue is staged through LDS (bf16 scatter into a 64-row x 512 B image,
// then coalesced dwordx4 full-line stores) to avoid the 2-byte global
// scatter that caused 97 MB WRITE_SIZE (RMW amplification) in round 5.
// ---------------------------------------------------------------------------
#define BM 128
#define BK 64
#define LDSTRIDE 144   // bytes per LDS row (128 data + 16 pad; 144 = 9*16)

__global__ __launch_bounds__(512) void gemm_and_buckets(
    const float* __restrict__ x, const unsigned short* __restrict__ wcatT,
    char* __restrict__ comb, int nrows,
    const int* __restrict__ er, const int* __restrict__ ec,
    const float* __restrict__ ev, int* __restrict__ cnt,
    unsigned* __restrict__ bucket4, int E, int bktBlocks) {
  __shared__ char smem[55296];           // As [0,18432) | Bs [18432,55296)
  char* As = smem;
  char* Bs = smem + 18432;

  if (blockIdx.x < bktBlocks) {
    // ---- bucket role: bucket4[r*CAP+idx] = {col:16 | bf16(val):16} ----
    const int stride = bktBlocks * 512;
    for (int e = blockIdx.x * 512 + threadIdx.x; e < E; e += stride) {
      const int r = er[e];
      const int idx = atomicAdd(&cnt[r], 1);
      if (idx < CAP)
        bucket4[(size_t)r * CAP + idx] =
            ((unsigned)ec[e] << 16) | (unsigned)f2bf(ev[e]);
    }
    return;
  }

  // ---- GEMM role ----
  const int t = threadIdx.x;
  const int lane = t & 63;
  const int wv = t >> 6;          // 0..7
  const int wr = wv >> 2;         // 0..1  (M half, 64 rows)
  const int wc = wv & 3;          // 0..3  (N quarter, 64 cols)
  const int blockRow = (blockIdx.x - bktBlocks) * BM;
  const int lrow = lane & 15;
  const int klane = lane >> 4;    // 0..3

  f32x4 acc[4][4];
#pragma unroll
  for (int m = 0; m < 4; ++m)
#pragma unroll
    for (int n = 0; n < 4; ++n) acc[m][n] = (f32x4){0.f, 0.f, 0.f, 0.f};

  const int arow = t >> 2;              // 0..127
  const int aseg = t & 3;               // 16 f32 each
  const int agrow = blockRow + arow;
  const bool aok = (agrow < nrows);
  const float* xrow = x + (size_t)agrow * IN_CH;

  const int bc = t >> 1;                // 0..255
  const int bhalf = t & 1;              // 0/1 (32 bf16 each)

  for (int kt = 0; kt < IN_CH; kt += BK) {
    // stage A: 128 rows x 64 k, f32 -> bf16
    {
      float4 v0 = make_float4(0, 0, 0, 0), v1 = v0, v2 = v0, v3 = v0;
      if (aok) {
        const float* p = xrow + kt + aseg * 16;
        v0 = *(const float4*)(p + 0);
        v1 = *(const float4*)(p + 4);
        v2 = *(const float4*)(p + 8);
        v3 = *(const float4*)(p + 12);
      }
      uint4 pk0, pk1;
      pk0.x = pack2bf(v0.x, v0.y); pk0.y = pack2bf(v0.z, v0.w);
      pk0.z = pack2bf(v1.x, v1.y); pk0.w = pack2bf(v1.z, v1.w);
      pk1.x = pack2bf(v2.x, v2.y); pk1.y = pack2bf(v2.z, v2.w);
      pk1.z = pack2bf(v3.x, v3.y); pk1.w = pack2bf(v3.z, v3.w);
      char* dst = As + arow * LDSTRIDE + aseg * 32;
      *(uint4*)(dst + 0)  = pk0;
      *(uint4*)(dst + 16) = pk1;
    }
    // stage B: 256 cols x 64 k bf16 from wcatT (already converted)
    {
      const char* src = (const char*)wcatT + (size_t)bc * 512 + kt * 2 + bhalf * 64;
      char* dst = Bs + bc * LDSTRIDE + bhalf * 64;
#pragma unroll
      for (int j = 0; j < 4; ++j)
        *(uint4*)(dst + j * 16) = *(const uint4*)(src + j * 16);
    }
    __syncthreads();

#pragma unroll
    for (int kk = 0; kk < 2; ++kk) {
      bf16x8 af[4], bfm[4];
#pragma unroll
      for (int m = 0; m < 4; ++m)
        af[m] = *(const bf16x8*)(As + (wr * 64 + m * 16 + lrow) * LDSTRIDE + kk * 64 + klane * 16);
#pragma unroll
      for (int n = 0; n < 4; ++n)
        bfm[n] = *(const bf16x8*)(Bs + (wc * 64 + n * 16 + lrow) * LDSTRIDE + kk * 64 + klane * 16);
#pragma unroll
      for (int m = 0; m < 4; ++m)
#pragma unroll
        for (int n = 0; n < 4; ++n)
          acc[m][n] = __builtin_amdgcn_mfma_f32_16x16x32_bf16(af[m], bfm[n], acc[m][n], 0, 0, 0);
    }
    __syncthreads();
  }

  // ---- epilogue: LDS-staged, 2 passes of 64 rows ----
  // D[row][col]: col=lane&15, row=(lane>>4)*4+j (m89-verified).
  // Pass h: waves with wr==h scatter bf16 into smem[0..32768) laid out as
  // 64 rows x 512 B (comb layout), then ALL threads store full lines.
#pragma unroll
  for (int h = 0; h < 2; ++h) {
    if (wr == h) {
#pragma unroll
      for (int m = 0; m < 4; ++m) {
#pragma unroll
        for (int n = 0; n < 4; ++n) {
#pragma unroll
          for (int j = 0; j < 4; ++j) {
            const int rl = m * 16 + klane * 4 + j;            // 0..63
            const int gcol = wc * 64 + n * 16 + lrow;         // 0..255
            const int ch = gcol & 127;
            const int isg = gcol >> 7;
            const int byteoff = (ch >> 1) * 8 + isg * 4 + (ch & 1) * 2;
            *(unsigned short*)(smem + rl * 512 + byteoff) = f2bf(acc[m][n][j]);
          }
        }
      }
    }
    __syncthreads();
#pragma unroll
    for (int it = 0; it < 4; ++it) {
      const int lin = it * 512 + t;       // float4 slot 0..2047
      const int rl = lin >> 5;            // 32 x 16B per row
      const int grow = blockRow + h * 64 + rl;
      if (grow < nrows)
        *(float4*)(comb + (size_t)grow * 512 + (lin & 31) * 16) =
            *(const float4*)(smem + lin * 16);
    }
    __syncthreads();
  }
}

// ---------------------------------------------------------------------------
// Fused SpMM x2 + sigmoid gate (round-3 verified form, 57 us).
// One wave per row; lane covers 2 channel-pairs (8 B). Whole edge set loaded
// in ONE coalesced read, then chunks of 8 independent gathers in flight.
// ---------------------------------------------------------------------------
__global__ __launch_bounds__(256) void spmm_fused(
    const unsigned* __restrict__ bucket4, const int* __restrict__ cnt,
    const char* __restrict__ comb, float* __restrict__ out, int nrows) {
  const int wid = (int)((blockIdx.x * 256 + threadIdx.x) >> 6);
  const int lane = threadIdx.x & 63;
  if (wid >= nrows) return;

  const int deg = min(cnt[wid], CAP);
  float s0 = 0.f, s1 = 0.f, g0 = 0.f, g1 = 0.f;

  if (deg > 0) {
    const unsigned my = bucket4[(size_t)wid * CAP + lane];   // lane d = edge d
    for (int d = 0; d < deg; d += 8) {
      unsigned cj[8]; float vj[8]; uint2 q[8];
#pragma unroll
      for (int j = 0; j < 8; ++j) {
        const int dj = d + j;
        const int ds = dj < deg ? dj : deg - 1;          // clamp (dup addr ~free)
        const unsigned ent = (unsigned)__shfl((int)my, ds);
        cj[j] = ent >> 16;
        vj[j] = (dj < deg) ? bflo(ent) : 0.f;
      }
#pragma unroll
      for (int j = 0; j < 8; ++j)
        q[j] = *(const uint2*)(comb + (size_t)cj[j] * 512 + lane * 8);
#pragma unroll
      for (int j = 0; j < 8; ++j) {
        s0 += vj[j] * bflo(q[j].x);  s1 += vj[j] * bfhi(q[j].x);
        g0 += vj[j] * bflo(q[j].y);  g1 += vj[j] * bfhi(q[j].y);
      }
    }
  }
  const float o0 = s0 / (1.f + __expf(-g0));
  const float o1 = s1 / (1.f + __expf(-g1));
  *(float2*)&out[(size_t)wid * OUT_CH + lane * 2] = make_float2(o0, o1);
}

extern "C" void kernel_launch(void* const* d_in, const int* in_sizes, int n_in,
                              void* d_out, int out_size, void* d_ws, size_t ws_size,
                              hipStream_t stream) {
  const float* x  = (const float*)d_in[0];
  const int*   er = (const int*)d_in[1];
  const int*   ec = (const int*)d_in[2];
  const float* ev = (const float*)d_in[3];
  const float* w  = (const float*)d_in[4];
  const float* gw = (const float*)d_in[5];
  float* out = (float*)d_out;

  const int N = in_sizes[0] / IN_CH;   // 50000
  const int E = in_sizes[1];           // 800000

  // workspace: comb [N*512 B] | wcatT [128 KB] | cnt [N*4] | bucket4 [N*CAP*4]
  char* ws = (char*)d_ws;
  char* comb = ws;
  size_t off = (size_t)N * 512;
  unsigned short* wcatT = (unsigned short*)(ws + off);  off += 256 * 256 * 2;
  int* cnt = (int*)(ws + off);                          off += (size_t)N * 4;
  unsigned* bucket4 = (unsigned*)(ws + off);

  // 1) init: cnt=0 + wcat build
  const int cntBlocks = (N + 255) / 256;
  init_and_wcat<<<cntBlocks + 256, 256, 0, stream>>>(w, gw, wcatT, cnt, N, cntBlocks);

  // 2) fused bucket scatter (first) + GEMM
  const int bktBlocks = 256;
  const int gemmBlocks = (N + BM - 1) / BM;   // full 256-col tiles
  gemm_and_buckets<<<bktBlocks + gemmBlocks, 512, 0, stream>>>(
      x, wcatT, comb, N, er, ec, ev, cnt, bucket4, E, bktBlocks);

  // 3) fused SpMM + gate
  const int blocks = (N + 3) / 4;   // 4 waves / 256-thr block
  spmm_fused<<<blocks, 256, 0, stream>>>(bucket4, cnt, comb, out, N);
}

// Round 7
// 117.097 us; speedup vs baseline: 1.1992x; 1.1992x over previous
//
#include <hip/hip_runtime.h>
#include <hip/hip_bf16.h>

#define IN_CH 256
#define OUT_CH 128
#define NCAT 256          // concatenated output channels (sup | gat)
#define CAP 64            // bucket capacity per row (Poisson(16): P(>64) ~ 1e-13)
#define RPB 128           // rows per coarse bin (bin = row >> 7)
#define BINCAP 3072       // entries per coarse bin (mean 2048, +22 sigma)
#define EPB 4096          // edges per pass-1 block

typedef __attribute__((ext_vector_type(8))) short bf16x8;
typedef __attribute__((ext_vector_type(4))) float f32x4;

__device__ __forceinline__ unsigned short f2bf(float f) {
  unsigned int u = __builtin_bit_cast(unsigned int, f);
  u += 0x7FFFu + ((u >> 16) & 1u);           // round-to-nearest-even
  return (unsigned short)(u >> 16);
}
__device__ __forceinline__ unsigned int pack2bf(float a, float b) {
  return (unsigned int)f2bf(a) | ((unsigned int)f2bf(b) << 16);
}
__device__ __forceinline__ float bflo(unsigned int u) {
  return __builtin_bit_cast(float, u << 16);
}
__device__ __forceinline__ float bfhi(unsigned int u) {
  return __builtin_bit_cast(float, u & 0xFFFF0000u);
}

// ---------------------------------------------------------------------------
// Init: blocks [0,256) build WcatT (bf16, [c][k], c<128 -> w, else gw);
// block 256 zeros coarse_cnt.
// ---------------------------------------------------------------------------
__global__ __launch_bounds__(256) void init_wcat(
    const float* __restrict__ w, const float* __restrict__ gw,
    unsigned short* __restrict__ wcatT, int* __restrict__ coarse_cnt,
    int nbins) {
  const int b = blockIdx.x;
  if (b < 256) {
    const int c = b;
    const int k = threadIdx.x;
    const float v = (c < 128) ? w[(size_t)k * 128 + c]
                              : gw[(size_t)k * 128 + (c - 128)];
    wcatT[(size_t)c * 256 + k] = f2bf(v);
  } else {
    for (int j = threadIdx.x; j < nbins; j += 256) coarse_cnt[j] = 0;
  }
}

// ---------------------------------------------------------------------------
// Pass 1: coarse binning by row>>7. Each block: 4096 edges, LDS histogram
// over <=512 bins, ONE global atomic per (block,bin), entries written into
// per-bin contiguous runs (~10 entries -> semi-coalesced). Replaces the
// 800K random 4B global scatter + cross-XCD line ping-pong of rounds 1-6.
// ---------------------------------------------------------------------------
__global__ __launch_bounds__(256) void bin_coarse(
    const int* __restrict__ er, const int* __restrict__ ec,
    const float* __restrict__ ev, int* __restrict__ coarse_cnt,
    unsigned* __restrict__ cA, unsigned char* __restrict__ cB,
    int E, int nbins) {
  __shared__ int scnt[512];
  __shared__ int sbase[512];
  const int t = threadIdx.x;
  const int e0 = blockIdx.x * EPB;

  for (int j = t; j < 512; j += 256) scnt[j] = 0;
  __syncthreads();

  int myr[16];
#pragma unroll
  for (int i = 0; i < 16; ++i) {
    const int e = e0 + i * 256 + t;
    int r = -1;
    if (e < E) { r = er[e]; atomicAdd(&scnt[r >> 7], 1); }
    myr[i] = r;
  }
  __syncthreads();

  for (int j = t; j < nbins; j += 256) {
    sbase[j] = (scnt[j] > 0) ? atomicAdd(&coarse_cnt[j], scnt[j]) : 0;
  }
  __syncthreads();
  for (int j = t; j < 512; j += 256) scnt[j] = 0;   // reuse as run counters
  __syncthreads();

#pragma unroll
  for (int i = 0; i < 16; ++i) {
    const int r = myr[i];
    if (r >= 0) {
      const int e = e0 + i * 256 + t;
      const int b = r >> 7;
      const int idx = sbase[b] + atomicAdd(&scnt[b], 1);
      if (idx < BINCAP) {
        const size_t g = (size_t)b * BINCAP + idx;
        cA[g] = ((unsigned)ec[e] << 16) | (unsigned)f2bf(ev[e]);
        cB[g] = (unsigned char)(r & (RPB - 1));
      }
    }
  }
}

// ---------------------------------------------------------------------------
// Pass 2: block b owns coarse bin b (128 rows). Read bin coalesced, LDS-
// atomic rank into a 32KB LDS bucket image, then coalesced write of bucket4
// (only used slots; per-row runs are line-aligned) + cnt.
// ---------------------------------------------------------------------------
__global__ __launch_bounds__(256) void bin_fine(
    const int* __restrict__ coarse_cnt, const unsigned* __restrict__ cA,
    const unsigned char* __restrict__ cB, int* __restrict__ cnt,
    unsigned* __restrict__ bucket4, int nrows) {
  __shared__ unsigned fine[RPB * CAP];   // 32768 B
  __shared__ int lcnt[RPB];
  const int t = threadIdx.x;
  const int b = blockIdx.x;
  const int r0 = b * RPB;

  for (int j = t; j < RPB; j += 256) lcnt[j] = 0;
  __syncthreads();

  const int nE = min(coarse_cnt[b], BINCAP);
  for (int i = t; i < nE; i += 256) {
    const unsigned a = cA[(size_t)b * BINCAP + i];
    const int rl = cB[(size_t)b * BINCAP + i];
    const int idx = atomicAdd(&lcnt[rl], 1);
    if (idx < CAP) fine[rl * CAP + idx] = a;
  }
  __syncthreads();

  if (t < RPB && r0 + t < nrows) cnt[r0 + t] = min(lcnt[t], CAP);

  for (int s = t; s < RPB * CAP; s += 256) {
    const int rl = s >> 6;              // CAP = 64
    const int sl = s & 63;
    if (sl < min(lcnt[rl], CAP) && r0 + rl < nrows)
      bucket4[(size_t)(r0 + rl) * CAP + sl] = fine[s];
  }
}

// ---------------------------------------------------------------------------
// MFMA GEMM (round-6 proven): comb = bf16(x) @ Wcat, tile 128 x 256.
// comb row r = 512 B; channel-pair p at byte 8p:
//   [sup_{2p}, sup_{2p+1}, gat_{2p}, gat_{2p+1}] bf16.
// Epilogue staged through LDS -> coalesced full-line dwordx4 stores.
// ---------------------------------------------------------------------------
#define BM 128
#define BK 64
#define LDSTRIDE 144   // bytes per LDS row (128 data + 16 pad; 2-way conflicts only)

__global__ __launch_bounds__(512) void gemm_mfma(
    const float* __restrict__ x, const unsigned short* __restrict__ wcatT,
    char* __restrict__ comb, int nrows) {
  __shared__ char smem[55296];           // As [0,18432) | Bs [18432,55296)
  char* As = smem;
  char* Bs = smem + 18432;

  const int t = threadIdx.x;
  const int lane = t & 63;
  const int wv = t >> 6;          // 0..7
  const int wr = wv >> 2;         // 0..1  (M half, 64 rows)
  const int wc = wv & 3;          // 0..3  (N quarter, 64 cols)
  const int blockRow = blockIdx.x * BM;
  const int lrow = lane & 15;
  const int klane = lane >> 4;    // 0..3

  f32x4 acc[4][4];
#pragma unroll
  for (int m = 0; m < 4; ++m)
#pragma unroll
    for (int n = 0; n < 4; ++n) acc[m][n] = (f32x4){0.f, 0.f, 0.f, 0.f};

  const int arow = t >> 2;              // 0..127
  const int aseg = t & 3;               // 16 f32 each
  const int agrow = blockRow + arow;
  const bool aok = (agrow < nrows);
  const float* xrow = x + (size_t)agrow * IN_CH;

  const int bc = t >> 1;                // 0..255
  const int bhalf = t & 1;              // 0/1 (32 bf16 each)

  for (int kt = 0; kt < IN_CH; kt += BK) {
    // stage A: 128 rows x 64 k, f32 -> bf16
    {
      float4 v0 = make_float4(0, 0, 0, 0), v1 = v0, v2 = v0, v3 = v0;
      if (aok) {
        const float* p = xrow + kt + aseg * 16;
        v0 = *(const float4*)(p + 0);
        v1 = *(const float4*)(p + 4);
        v2 = *(const float4*)(p + 8);
        v3 = *(const float4*)(p + 12);
      }
      uint4 pk0, pk1;
      pk0.x = pack2bf(v0.x, v0.y); pk0.y = pack2bf(v0.z, v0.w);
      pk0.z = pack2bf(v1.x, v1.y); pk0.w = pack2bf(v1.z, v1.w);
      pk1.x = pack2bf(v2.x, v2.y); pk1.y = pack2bf(v2.z, v2.w);
      pk1.z = pack2bf(v3.x, v3.y); pk1.w = pack2bf(v3.z, v3.w);
      char* dst = As + arow * LDSTRIDE + aseg * 32;
      *(uint4*)(dst + 0)  = pk0;
      *(uint4*)(dst + 16) = pk1;
    }
    // stage B: 256 cols x 64 k bf16 from wcatT (already converted)
    {
      const char* src = (const char*)wcatT + (size_t)bc * 512 + kt * 2 + bhalf * 64;
      char* dst = Bs + bc * LDSTRIDE + bhalf * 64;
#pragma unroll
      for (int j = 0; j < 4; ++j)
        *(uint4*)(dst + j * 16) = *(const uint4*)(src + j * 16);
    }
    __syncthreads();

#pragma unroll
    for (int kk = 0; kk < 2; ++kk) {
      bf16x8 af[4], bfm[4];
#pragma unroll
      for (int m = 0; m < 4; ++m)
        af[m] = *(const bf16x8*)(As + (wr * 64 + m * 16 + lrow) * LDSTRIDE + kk * 64 + klane * 16);
#pragma unroll
      for (int n = 0; n < 4; ++n)
        bfm[n] = *(const bf16x8*)(Bs + (wc * 64 + n * 16 + lrow) * LDSTRIDE + kk * 64 + klane * 16);
#pragma unroll
      for (int m = 0; m < 4; ++m)
#pragma unroll
        for (int n = 0; n < 4; ++n)
          acc[m][n] = __builtin_amdgcn_mfma_f32_16x16x32_bf16(af[m], bfm[n], acc[m][n], 0, 0, 0);
    }
    __syncthreads();
  }

  // epilogue: LDS-staged, 2 passes of 64 rows.
  // D[row][col]: col=lane&15, row=(lane>>4)*4+j (m89-verified).
#pragma unroll
  for (int h = 0; h < 2; ++h) {
    if (wr == h) {
#pragma unroll
      for (int m = 0; m < 4; ++m) {
#pragma unroll
        for (int n = 0; n < 4; ++n) {
#pragma unroll
          for (int j = 0; j < 4; ++j) {
            const int rl = m * 16 + klane * 4 + j;            // 0..63
            const int gcol = wc * 64 + n * 16 + lrow;         // 0..255
            const int ch = gcol & 127;
            const int isg = gcol >> 7;
            const int byteoff = (ch >> 1) * 8 + isg * 4 + (ch & 1) * 2;
            *(unsigned short*)(smem + rl * 512 + byteoff) = f2bf(acc[m][n][j]);
          }
        }
      }
    }
    __syncthreads();
#pragma unroll
    for (int it = 0; it < 4; ++it) {
      const int lin = it * 512 + t;       // float4 slot 0..2047
      const int rl = lin >> 5;            // 32 x 16B per row
      const int grow = blockRow + h * 64 + rl;
      if (grow < nrows)
        *(float4*)(comb + (size_t)grow * 512 + (lin & 31) * 16) =
            *(const float4*)(smem + lin * 16);
    }
    __syncthreads();
  }
}

// ---------------------------------------------------------------------------
// Fused SpMM x2 + sigmoid gate (round-3 proven form, 57 us).
// One wave per row; lane covers 2 channel-pairs (8 B). Whole edge set loaded
// in ONE coalesced read, then chunks of 8 independent gathers in flight.
// ---------------------------------------------------------------------------
__global__ __launch_bounds__(256) void spmm_fused(
    const unsigned* __restrict__ bucket4, const int* __restrict__ cnt,
    const char* __restrict__ comb, float* __restrict__ out, int nrows) {
  const int wid = (int)((blockIdx.x * 256 + threadIdx.x) >> 6);
  const int lane = threadIdx.x & 63;
  if (wid >= nrows) return;

  const int deg = min(cnt[wid], CAP);
  float s0 = 0.f, s1 = 0.f, g0 = 0.f, g1 = 0.f;

  if (deg > 0) {
    const unsigned my = bucket4[(size_t)wid * CAP + lane];   // lane d = edge d
    for (int d = 0; d < deg; d += 8) {
      unsigned cj[8]; float vj[8]; uint2 q[8];
#pragma unroll
      for (int j = 0; j < 8; ++j) {
        const int dj = d + j;
        const int ds = dj < deg ? dj : deg - 1;          // clamp (dup addr ~free)
        const unsigned ent = (unsigned)__shfl((int)my, ds);
        cj[j] = ent >> 16;
        vj[j] = (dj < deg) ? bflo(ent) : 0.f;
      }
#pragma unroll
      for (int j = 0; j < 8; ++j)
        q[j] = *(const uint2*)(comb + (size_t)cj[j] * 512 + lane * 8);
#pragma unroll
      for (int j = 0; j < 8; ++j) {
        s0 += vj[j] * bflo(q[j].x);  s1 += vj[j] * bfhi(q[j].x);
        g0 += vj[j] * bflo(q[j].y);  g1 += vj[j] * bfhi(q[j].y);
      }
    }
  }
  const float o0 = s0 / (1.f + __expf(-g0));
  const float o1 = s1 / (1.f + __expf(-g1));
  *(float2*)&out[(size_t)wid * OUT_CH + lane * 2] = make_float2(o0, o1);
}

extern "C" void kernel_launch(void* const* d_in, const int* in_sizes, int n_in,
                              void* d_out, int out_size, void* d_ws, size_t ws_size,
                              hipStream_t stream) {
  const float* x  = (const float*)d_in[0];
  const int*   er = (const int*)d_in[1];
  const int*   ec = (const int*)d_in[2];
  const float* ev = (const float*)d_in[3];
  const float* w  = (const float*)d_in[4];
  const float* gw = (const float*)d_in[5];
  float* out = (float*)d_out;

  const int N = in_sizes[0] / IN_CH;   // 50000
  const int E = in_sizes[1];           // 800000
  const int nbins = (N + RPB - 1) / RPB;   // 391

  // workspace layout (all 256B-aligned):
  // comb [N*512] | wcatT [128K] | cnt [N*4] | bucket4 [N*CAP*4]
  // | coarse_cnt [nbins*4] | cA [nbins*BINCAP*4] | cB [nbins*BINCAP]
  char* ws = (char*)d_ws;
  char* comb = ws;
  size_t off = (size_t)N * 512;
  unsigned short* wcatT = (unsigned short*)(ws + off);  off += 256 * 256 * 2;
  int* cnt = (int*)(ws + off);                          off += ((size_t)N * 4 + 255) & ~255ull;
  unsigned* bucket4 = (unsigned*)(ws + off);            off += (size_t)N * CAP * 4;
  int* coarse_cnt = (int*)(ws + off);                   off += ((size_t)nbins * 4 + 255) & ~255ull;
  unsigned* cA = (unsigned*)(ws + off);                 off += (size_t)nbins * BINCAP * 4;
  unsigned char* cB = (unsigned char*)(ws + off);

  // 1) wcat build + coarse_cnt zero
  init_wcat<<<257, 256, 0, stream>>>(w, gw, wcatT, coarse_cnt, nbins);

  // 2) coarse binning (row>>7)
  const int p1Blocks = (E + EPB - 1) / EPB;
  bin_coarse<<<p1Blocks, 256, 0, stream>>>(er, ec, ev, coarse_cnt, cA, cB, E, nbins);

  // 3) fine binning -> bucket4 + cnt (coalesced writes)
  bin_fine<<<nbins, 256, 0, stream>>>(coarse_cnt, cA, cB, cnt, bucket4, N);

  // 4) GEMM
  const int gemmBlocks = (N + BM - 1) / BM;
  gemm_mfma<<<gemmBlocks, 512, 0, stream>>>(x, wcatT, comb, N);

  // 5) fused SpMM + gate
  const int blocks = (N + 3) / 4;   // 4 waves / 256-thr block
  spmm_fused<<<blocks, 256, 0, stream>>>(bucket4, cnt, comb, out, N);
}

// Round 8
// 109.731 us; speedup vs baseline: 1.2797x; 1.0671x over previous
//
#include <hip/hip_runtime.h>
#include <hip/hip_bf16.h>

#define IN_CH 256
#define OUT_CH 128
#define NCAT 256          // concatenated output channels (sup | gat)
#define CAP 64            // bucket capacity per row (Poisson(16): P(>64) ~ 1e-13)
#define RPB 128           // rows per coarse bin (bin = row >> 7)
#define BINCAP 3072       // entries per coarse bin (mean 2048, +22 sigma)
#define EPB 4096          // edges per bin-role block

typedef __attribute__((ext_vector_type(8))) short bf16x8;
typedef __attribute__((ext_vector_type(4))) float f32x4;

__device__ __forceinline__ unsigned short f2bf(float f) {
  unsigned int u = __builtin_bit_cast(unsigned int, f);
  u += 0x7FFFu + ((u >> 16) & 1u);           // round-to-nearest-even
  return (unsigned short)(u >> 16);
}
__device__ __forceinline__ unsigned int pack2bf(float a, float b) {
  return (unsigned int)f2bf(a) | ((unsigned int)f2bf(b) << 16);
}
__device__ __forceinline__ float bflo(unsigned int u) {
  return __builtin_bit_cast(float, u << 16);
}
__device__ __forceinline__ float bfhi(unsigned int u) {
  return __builtin_bit_cast(float, u & 0xFFFF0000u);
}

// ---------------------------------------------------------------------------
// Init: blocks [0,256) build WcatT (bf16, [c][k], c<128 -> w, else gw);
// block 256 zeros coarse_cnt.
// ---------------------------------------------------------------------------
__global__ __launch_bounds__(256) void init_wcat(
    const float* __restrict__ w, const float* __restrict__ gw,
    unsigned short* __restrict__ wcatT, int* __restrict__ coarse_cnt,
    int nbins) {
  const int b = blockIdx.x;
  if (b < 256) {
    const int c = b;
    const int k = threadIdx.x;
    const float v = (c < 128) ? w[(size_t)k * 128 + c]
                              : gw[(size_t)k * 128 + (c - 128)];
    wcatT[(size_t)c * 256 + k] = f2bf(v);
  } else {
    for (int j = threadIdx.x; j < nbins; j += 256) coarse_cnt[j] = 0;
  }
}

// ---------------------------------------------------------------------------
// FAT kernel. Blocks [0, binBlocks): coarse edge binning (row>>7) — LDS
// histogram, one global atomic per (block,bin), semi-coalesced run writes.
// Blocks [binBlocks, +gemmBlocks): MFMA GEMM comb = bf16(x) @ Wcat.
// The two roles are data-independent; at 2 blocks/CU all 587 blocks are
// co-resident, so binning hides entirely under the latency-bound GEMM.
//
// comb layout: row r = 512 B; channel-pair p at byte 8p:
//   [sup_{2p}, sup_{2p+1}, gat_{2p}, gat_{2p+1}] bf16.
// GEMM epilogue staged through LDS -> coalesced full-line dwordx4 stores
// (round-6 proven; avoids 2-byte global scatter RMW).
// ---------------------------------------------------------------------------
#define BM 128
#define BK 64
#define LDSTRIDE 144   // bytes per LDS row (128 data + 16 pad; 2-way conflicts only)

__global__ __launch_bounds__(512) void gemm_and_bin(
    const float* __restrict__ x, const unsigned short* __restrict__ wcatT,
    char* __restrict__ comb, int nrows,
    const int* __restrict__ er, const int* __restrict__ ec,
    const float* __restrict__ ev, int* __restrict__ coarse_cnt,
    unsigned* __restrict__ cA, unsigned char* __restrict__ cB,
    int E, int nbins, int binBlocks) {
  __shared__ char smem[55296];           // gemm: As|Bs ; bin: scnt|sbase

  if (blockIdx.x < binBlocks) {
    // ---- bin role (round-7 bin_coarse verbatim, 512 threads) ----
    int* scnt = (int*)smem;              // [512]
    int* sbase = (int*)smem + 512;       // [512]
    const int t = threadIdx.x;
    const int e0 = blockIdx.x * EPB;

    if (t < 512) scnt[t] = 0;
    __syncthreads();

    int myr[8];
#pragma unroll
    for (int i = 0; i < 8; ++i) {
      const int e = e0 + i * 512 + t;
      int r = -1;
      if (e < E) { r = er[e]; atomicAdd(&scnt[r >> 7], 1); }
      myr[i] = r;
    }
    __syncthreads();

    if (t < nbins)
      sbase[t] = (scnt[t] > 0) ? atomicAdd(&coarse_cnt[t], scnt[t]) : 0;
    __syncthreads();
    if (t < 512) scnt[t] = 0;            // reuse as run counters
    __syncthreads();

#pragma unroll
    for (int i = 0; i < 8; ++i) {
      const int r = myr[i];
      if (r >= 0) {
        const int e = e0 + i * 512 + t;
        const int b = r >> 7;
        const int idx = sbase[b] + atomicAdd(&scnt[b], 1);
        if (idx < BINCAP) {
          const size_t g = (size_t)b * BINCAP + idx;
          cA[g] = ((unsigned)ec[e] << 16) | (unsigned)f2bf(ev[e]);
          cB[g] = (unsigned char)(r & (RPB - 1));
        }
      }
    }
    return;
  }

  // ---- GEMM role (round-7 proven) ----
  char* As = smem;
  char* Bs = smem + 18432;

  const int t = threadIdx.x;
  const int lane = t & 63;
  const int wv = t >> 6;          // 0..7
  const int wr = wv >> 2;         // 0..1  (M half, 64 rows)
  const int wc = wv & 3;          // 0..3  (N quarter, 64 cols)
  const int blockRow = (blockIdx.x - binBlocks) * BM;
  const int lrow = lane & 15;
  const int klane = lane >> 4;    // 0..3

  f32x4 acc[4][4];
#pragma unroll
  for (int m = 0; m < 4; ++m)
#pragma unroll
    for (int n = 0; n < 4; ++n) acc[m][n] = (f32x4){0.f, 0.f, 0.f, 0.f};

  const int arow = t >> 2;              // 0..127
  const int aseg = t & 3;               // 16 f32 each
  const int agrow = blockRow + arow;
  const bool aok = (agrow < nrows);
  const float* xrow = x + (size_t)agrow * IN_CH;

  const int bc = t >> 1;                // 0..255
  const int bhalf = t & 1;              // 0/1 (32 bf16 each)

  for (int kt = 0; kt < IN_CH; kt += BK) {
    // stage A: 128 rows x 64 k, f32 -> bf16
    {
      float4 v0 = make_float4(0, 0, 0, 0), v1 = v0, v2 = v0, v3 = v0;
      if (aok) {
        const float* p = xrow + kt + aseg * 16;
        v0 = *(const float4*)(p + 0);
        v1 = *(const float4*)(p + 4);
        v2 = *(const float4*)(p + 8);
        v3 = *(const float4*)(p + 12);
      }
      uint4 pk0, pk1;
      pk0.x = pack2bf(v0.x, v0.y); pk0.y = pack2bf(v0.z, v0.w);
      pk0.z = pack2bf(v1.x, v1.y); pk0.w = pack2bf(v1.z, v1.w);
      pk1.x = pack2bf(v2.x, v2.y); pk1.y = pack2bf(v2.z, v2.w);
      pk1.z = pack2bf(v3.x, v3.y); pk1.w = pack2bf(v3.z, v3.w);
      char* dst = As + arow * LDSTRIDE + aseg * 32;
      *(uint4*)(dst + 0)  = pk0;
      *(uint4*)(dst + 16) = pk1;
    }
    // stage B: 256 cols x 64 k bf16 from wcatT (already converted)
    {
      const char* src = (const char*)wcatT + (size_t)bc * 512 + kt * 2 + bhalf * 64;
      char* dst = Bs + bc * LDSTRIDE + bhalf * 64;
#pragma unroll
      for (int j = 0; j < 4; ++j)
        *(uint4*)(dst + j * 16) = *(const uint4*)(src + j * 16);
    }
    __syncthreads();

#pragma unroll
    for (int kk = 0; kk < 2; ++kk) {
      bf16x8 af[4], bfm[4];
#pragma unroll
      for (int m = 0; m < 4; ++m)
        af[m] = *(const bf16x8*)(As + (wr * 64 + m * 16 + lrow) * LDSTRIDE + kk * 64 + klane * 16);
#pragma unroll
      for (int n = 0; n < 4; ++n)
        bfm[n] = *(const bf16x8*)(Bs + (wc * 64 + n * 16 + lrow) * LDSTRIDE + kk * 64 + klane * 16);
#pragma unroll
      for (int m = 0; m < 4; ++m)
#pragma unroll
        for (int n = 0; n < 4; ++n)
          acc[m][n] = __builtin_amdgcn_mfma_f32_16x16x32_bf16(af[m], bfm[n], acc[m][n], 0, 0, 0);
    }
    __syncthreads();
  }

  // epilogue: LDS-staged, 2 passes of 64 rows.
  // D[row][col]: col=lane&15, row=(lane>>4)*4+j (m89-verified).
#pragma unroll
  for (int h = 0; h < 2; ++h) {
    if (wr == h) {
#pragma unroll
      for (int m = 0; m < 4; ++m) {
#pragma unroll
        for (int n = 0; n < 4; ++n) {
#pragma unroll
          for (int j = 0; j < 4; ++j) {
            const int rl = m * 16 + klane * 4 + j;            // 0..63
            const int gcol = wc * 64 + n * 16 + lrow;         // 0..255
            const int ch = gcol & 127;
            const int isg = gcol >> 7;
            const int byteoff = (ch >> 1) * 8 + isg * 4 + (ch & 1) * 2;
            *(unsigned short*)(smem + rl * 512 + byteoff) = f2bf(acc[m][n][j]);
          }
        }
      }
    }
    __syncthreads();
#pragma unroll
    for (int it = 0; it < 4; ++it) {
      const int lin = it * 512 + t;       // float4 slot 0..2047
      const int rl = lin >> 5;            // 32 x 16B per row
      const int grow = blockRow + h * 64 + rl;
      if (grow < nrows)
        *(float4*)(comb + (size_t)grow * 512 + (lin & 31) * 16) =
            *(const float4*)(smem + lin * 16);
    }
    __syncthreads();
  }
}

// ---------------------------------------------------------------------------
// Pass 2: block b owns coarse bin b (128 rows). Read bin coalesced, LDS-
// atomic rank into a 32KB LDS bucket image, then coalesced write of bucket4
// + cnt.
// ---------------------------------------------------------------------------
__global__ __launch_bounds__(256) void bin_fine(
    const int* __restrict__ coarse_cnt, const unsigned* __restrict__ cA,
    const unsigned char* __restrict__ cB, int* __restrict__ cnt,
    unsigned* __restrict__ bucket4, int nrows) {
  __shared__ unsigned fine[RPB * CAP];   // 32768 B
  __shared__ int lcnt[RPB];
  const int t = threadIdx.x;
  const int b = blockIdx.x;
  const int r0 = b * RPB;

  for (int j = t; j < RPB; j += 256) lcnt[j] = 0;
  __syncthreads();

  const int nE = min(coarse_cnt[b], BINCAP);
  for (int i = t; i < nE; i += 256) {
    const unsigned a = cA[(size_t)b * BINCAP + i];
    const int rl = cB[(size_t)b * BINCAP + i];
    const int idx = atomicAdd(&lcnt[rl], 1);
    if (idx < CAP) fine[rl * CAP + idx] = a;
  }
  __syncthreads();

  if (t < RPB && r0 + t < nrows) cnt[r0 + t] = min(lcnt[t], CAP);

  for (int s = t; s < RPB * CAP; s += 256) {
    const int rl = s >> 6;              // CAP = 64
    const int sl = s & 63;
    if (sl < min(lcnt[rl], CAP) && r0 + rl < nrows)
      bucket4[(size_t)(r0 + rl) * CAP + sl] = fine[s];
  }
}

// ---------------------------------------------------------------------------
// Fused SpMM x2 + sigmoid gate (proven form, ~55 us).
// One wave per row; lane covers 2 channel-pairs (8 B). Whole edge set loaded
// in ONE coalesced read, then chunks of 8 independent gathers in flight.
// ---------------------------------------------------------------------------
__global__ __launch_bounds__(256) void spmm_fused(
    const unsigned* __restrict__ bucket4, const int* __restrict__ cnt,
    const char* __restrict__ comb, float* __restrict__ out, int nrows) {
  const int wid = (int)((blockIdx.x * 256 + threadIdx.x) >> 6);
  const int lane = threadIdx.x & 63;
  if (wid >= nrows) return;

  const int deg = min(cnt[wid], CAP);
  float s0 = 0.f, s1 = 0.f, g0 = 0.f, g1 = 0.f;

  if (deg > 0) {
    const unsigned my = bucket4[(size_t)wid * CAP + lane];   // lane d = edge d
    for (int d = 0; d < deg; d += 8) {
      unsigned cj[8]; float vj[8]; uint2 q[8];
#pragma unroll
      for (int j = 0; j < 8; ++j) {
        const int dj = d + j;
        const int ds = dj < deg ? dj : deg - 1;          // clamp (dup addr ~free)
        const unsigned ent = (unsigned)__shfl((int)my, ds);
        cj[j] = ent >> 16;
        vj[j] = (dj < deg) ? bflo(ent) : 0.f;
      }
#pragma unroll
      for (int j = 0; j < 8; ++j)
        q[j] = *(const uint2*)(comb + (size_t)cj[j] * 512 + lane * 8);
#pragma unroll
      for (int j = 0; j < 8; ++j) {
        s0 += vj[j] * bflo(q[j].x);  s1 += vj[j] * bfhi(q[j].x);
        g0 += vj[j] * bflo(q[j].y);  g1 += vj[j] * bfhi(q[j].y);
      }
    }
  }
  const float o0 = s0 / (1.f + __expf(-g0));
  const float o1 = s1 / (1.f + __expf(-g1));
  *(float2*)&out[(size_t)wid * OUT_CH + lane * 2] = make_float2(o0, o1);
}

extern "C" void kernel_launch(void* const* d_in, const int* in_sizes, int n_in,
                              void* d_out, int out_size, void* d_ws, size_t ws_size,
                              hipStream_t stream) {
  const float* x  = (const float*)d_in[0];
  const int*   er = (const int*)d_in[1];
  const int*   ec = (const int*)d_in[2];
  const float* ev = (const float*)d_in[3];
  const float* w  = (const float*)d_in[4];
  const float* gw = (const float*)d_in[5];
  float* out = (float*)d_out;

  const int N = in_sizes[0] / IN_CH;   // 50000
  const int E = in_sizes[1];           // 800000
  const int nbins = (N + RPB - 1) / RPB;   // 391 (must be <= 512)

  // workspace layout (256B-aligned):
  // comb [N*512] | wcatT [128K] | cnt [N*4] | bucket4 [N*CAP*4]
  // | coarse_cnt [nbins*4] | cA [nbins*BINCAP*4] | cB [nbins*BINCAP]
  char* ws = (char*)d_ws;
  char* comb = ws;
  size_t off = (size_t)N * 512;
  unsigned short* wcatT = (unsigned short*)(ws + off);  off += 256 * 256 * 2;
  int* cnt = (int*)(ws + off);                          off += ((size_t)N * 4 + 255) & ~255ull;
  unsigned* bucket4 = (unsigned*)(ws + off);            off += (size_t)N * CAP * 4;
  int* coarse_cnt = (int*)(ws + off);                   off += ((size_t)nbins * 4 + 255) & ~255ull;
  unsigned* cA = (unsigned*)(ws + off);                 off += (size_t)nbins * BINCAP * 4;
  unsigned char* cB = (unsigned char*)(ws + off);

  // 1) wcat build + coarse_cnt zero
  init_wcat<<<257, 256, 0, stream>>>(w, gw, wcatT, coarse_cnt, nbins);

  // 2) FAT: coarse binning (blocks 0..binBlocks) + GEMM (rest)
  const int binBlocks = (E + EPB - 1) / EPB;          // 196
  const int gemmBlocks = (N + BM - 1) / BM;           // 391
  gemm_and_bin<<<binBlocks + gemmBlocks, 512, 0, stream>>>(
      x, wcatT, comb, N, er, ec, ev, coarse_cnt, cA, cB, E, nbins, binBlocks);

  // 3) fine binning -> bucket4 + cnt
  bin_fine<<<nbins, 256, 0, stream>>>(coarse_cnt, cA, cB, cnt, bucket4, N);

  // 4) fused SpMM + gate
  const int blocks = (N + 3) / 4;   // 4 waves / 256-thr block
  spmm_fused<<<blocks, 256, 0, stream>>>(bucket4, cnt, comb, out, N);
}